// Round 1
// baseline (1772.099 us; speedup 1.0000x reference)
//
#include <hip/hip_runtime.h>
#include <math.h>

#define PIX 36864          // 192*192
#define IMW 192
#define NWIN 4465          // 47*95
#define NWIN_W 95

// ======================= complex GEMM =======================
// Y[o,p] = sum_c W[o,c] * X[c,p]  (complex; W: (M,K) row-major, X: (K,N), Y: (M,N))
#define GTM 32
#define GTN 64
#define GTK 16

__global__ __launch_bounds__(256) void cgemm_kernel(
    const float* __restrict__ Wr, const float* __restrict__ Wi,
    const float* __restrict__ Xr, const float* __restrict__ Xi,
    float* __restrict__ Yr, float* __restrict__ Yi,
    int M, int K, int N)
{
    __shared__ float sWr[GTM][GTK + 1];
    __shared__ float sWi[GTM][GTK + 1];
    __shared__ float sXr[GTK][GTN];
    __shared__ float sXi[GTK][GTN];

    const int tid = threadIdx.x;
    const int tx = tid & 15;   // pixel group (4 pixels)
    const int ty = tid >> 4;   // o group (2 outputs)
    const int p0 = blockIdx.x * GTN;
    const int o0 = blockIdx.y * GTM;

    float aR[2][4] = {{0.f,0.f,0.f,0.f},{0.f,0.f,0.f,0.f}};
    float aI[2][4] = {{0.f,0.f,0.f,0.f},{0.f,0.f,0.f,0.f}};

    for (int k0 = 0; k0 < K; k0 += GTK) {
#pragma unroll
        for (int j = 0; j < 2; ++j) {              // 512 W elems per matrix
            int e = tid + j * 256;
            int o = e >> 4;
            int kk = e & 15;
            sWr[o][kk] = Wr[(size_t)(o0 + o) * K + k0 + kk];
            sWi[o][kk] = Wi[(size_t)(o0 + o) * K + k0 + kk];
        }
#pragma unroll
        for (int j = 0; j < 4; ++j) {              // 1024 X elems per matrix
            int e = tid + j * 256;
            int kk = e >> 6;
            int p = e & 63;
            sXr[kk][p] = Xr[(size_t)(k0 + kk) * N + p0 + p];
            sXi[kk][p] = Xi[(size_t)(k0 + kk) * N + p0 + p];
        }
        __syncthreads();
#pragma unroll
        for (int kk = 0; kk < GTK; ++kk) {
            float wr0 = sWr[ty*2][kk],   wi0 = sWi[ty*2][kk];
            float wr1 = sWr[ty*2+1][kk], wi1 = sWi[ty*2+1][kk];
            const float4 xr4 = *(const float4*)&sXr[kk][tx*4];
            const float4 xi4 = *(const float4*)&sXi[kk][tx*4];
            const float xr[4] = {xr4.x, xr4.y, xr4.z, xr4.w};
            const float xi[4] = {xi4.x, xi4.y, xi4.z, xi4.w};
#pragma unroll
            for (int b = 0; b < 4; ++b) {
                aR[0][b] += wr0 * xr[b] - wi0 * xi[b];
                aI[0][b] += wr0 * xi[b] + wi0 * xr[b];
                aR[1][b] += wr1 * xr[b] - wi1 * xi[b];
                aI[1][b] += wr1 * xi[b] + wi1 * xr[b];
            }
        }
        __syncthreads();
    }
#pragma unroll
    for (int a = 0; a < 2; ++a) {
        size_t base = (size_t)(o0 + ty*2 + a) * N + p0 + tx*4;
        float4 vr = {aR[a][0], aR[a][1], aR[a][2], aR[a][3]};
        float4 vi = {aI[a][0], aI[a][1], aI[a][2], aI[a][3]};
        *(float4*)&Yr[base] = vr;
        *(float4*)&Yi[base] = vi;
    }
}

// ======================= attention per (window, head) =======================
// Gathers q,k,v (16 ch x 32 pix complex) from the per-pixel qkv buffer,
// computes attn = scale*q·conj(k)^T + rel-bias (real), magnitude-softmax
// reweighting, out = attn·v, scatter-adds PRE-proj output into fold buffer.
__global__ __launch_bounds__(256) void attn_kernel(
    const float* __restrict__ qkv_r, const float* __restrict__ qkv_i,
    const float* __restrict__ rel,
    float* __restrict__ fold_r, float* __restrict__ fold_i)
{
    const int blk = blockIdx.x;
    const int h  = blk % 6;
    const int w  = blk / 6;
    const int nh = w / NWIN_W;
    const int nw = w % NWIN_W;
    const int r0 = nh * 4, c0 = nw * 2;

    __shared__ float sQ[2][16][36];
    __shared__ float sK[2][16][36];
    __shared__ float sV[2][16][36];
    __shared__ float sA[2][32][36];

    const int tid = threadIdx.x;

    // load: 6 planes (qr,qi,kr,ki,vr,vi) x 16 d x 32 p = 3072 elements
#pragma unroll
    for (int j = 0; j < 12; ++j) {
        int e = tid + j * 256;
        int mat   = e >> 9;       // 0..5
        int idx   = e & 511;
        int d     = idx >> 5;
        int p     = idx & 31;
        int comp  = mat & 1;      // 0 = real, 1 = imag
        int which = mat >> 1;     // 0 q, 1 k, 2 v
        int ch = which * 96 + h * 16 + d;
        const float* src = comp ? qkv_i : qkv_r;
        float val = src[(size_t)ch * PIX + (size_t)(r0 + (p >> 2)) * IMW + c0 + (p & 3)];
        if (which == 0)      sQ[comp][d][p] = val;
        else if (which == 1) sK[comp][d][p] = val;
        else                 sV[comp][d][p] = val;
    }
    __syncthreads();

    // attn: thread -> row n = tid>>3, 4 cols starting at mb
    const int n  = tid >> 3;
    const int mb = (tid & 7) * 4;
    float ar[4] = {0.f,0.f,0.f,0.f}, ai[4] = {0.f,0.f,0.f,0.f};
#pragma unroll
    for (int d = 0; d < 16; ++d) {
        float qr = sQ[0][d][n], qi = sQ[1][d][n];
        const float4 kr4 = *(const float4*)&sK[0][d][mb];
        const float4 ki4 = *(const float4*)&sK[1][d][mb];
        const float krv[4] = {kr4.x, kr4.y, kr4.z, kr4.w};
        const float kiv[4] = {ki4.x, ki4.y, ki4.z, ki4.w};
#pragma unroll
        for (int jj = 0; jj < 4; ++jj) {
            ar[jj] += qr * krv[jj] + qi * kiv[jj];   // q * conj(k)
            ai[jj] += qi * krv[jj] - qr * kiv[jj];
        }
    }
    const int yn = n >> 2, xn = n & 3;
    float mag[4];
#pragma unroll
    for (int jj = 0; jj < 4; ++jj) {
        int m = mb + jj;
        int ym = m >> 2, xm = m & 3;
        int ridx = (yn - ym + 7) * 7 + (xn - xm + 3);
        ar[jj] = ar[jj] * 0.25f + rel[h * 105 + ridx];  // scale, bias (real only)
        ai[jj] *= 0.25f;
        mag[jj] = sqrtf(ar[jj]*ar[jj] + ai[jj]*ai[jj]);
    }
    // softmax over the 32 mags of row n (8 lanes x 4 each)
    float mx = fmaxf(fmaxf(mag[0], mag[1]), fmaxf(mag[2], mag[3]));
#pragma unroll
    for (int off = 1; off < 8; off <<= 1)
        mx = fmaxf(mx, __shfl_xor(mx, off, 64));
    float es[4], ssum = 0.f;
#pragma unroll
    for (int jj = 0; jj < 4; ++jj) { es[jj] = expf(mag[jj] - mx); ssum += es[jj]; }
#pragma unroll
    for (int off = 1; off < 8; off <<= 1)
        ssum += __shfl_xor(ssum, off, 64);
    const float inv = 1.0f / ssum;
#pragma unroll
    for (int jj = 0; jj < 4; ++jj) {
        float f = es[jj] * inv / (mag[jj] + 1e-8f);
        sA[0][n][mb + jj] = ar[jj] * f;
        sA[1][n][mb + jj] = ai[jj] * f;
    }
    __syncthreads();

    // out[n,d] = sum_m attn[n,m] * v[m,d]; thread -> (n1,dd) and (n1+16,dd)
    const int dd = tid & 15;
    const int n1 = tid >> 4;
    const int n2 = n1 + 16;
    float o1r = 0.f, o1i = 0.f, o2r = 0.f, o2i = 0.f;
#pragma unroll
    for (int m = 0; m < 32; ++m) {
        float vr = sV[0][dd][m], vi = sV[1][dd][m];
        float a1r = sA[0][n1][m], a1i = sA[1][n1][m];
        float a2r = sA[0][n2][m], a2i = sA[1][n2][m];
        o1r += a1r * vr - a1i * vi;  o1i += a1r * vi + a1i * vr;
        o2r += a2r * vr - a2i * vi;  o2i += a2r * vi + a2i * vr;
    }
    const int ch = h * 16 + dd;
    size_t base = (size_t)ch * PIX;
    int g1 = (r0 + (n1 >> 2)) * IMW + c0 + (n1 & 3);
    int g2 = (r0 + (n2 >> 2)) * IMW + c0 + (n2 & 3);
    atomicAdd(&fold_r[base + g1], o1r);
    atomicAdd(&fold_i[base + g1], o1i);
    atomicAdd(&fold_r[base + g2], o2r);
    atomicAdd(&fold_i[base + g2], o2i);
}

// ======================= elementwise / BN =======================
// s = x + proj / (count + eps)   (count analytic from overlap pattern)
__global__ __launch_bounds__(256) void combine1_kernel(
    const float* __restrict__ xr, const float* __restrict__ xi,
    const float* __restrict__ pr, const float* __restrict__ pi,
    float* __restrict__ sr, float* __restrict__ si)
{
    int e = blockIdx.x * 256 + threadIdx.x;
    if (e >= 96 * PIX) return;
    int g = e % PIX;
    int r = g / IMW, c = g % IMW;
    int kmin = (r >= 7) ? ((r - 4) >> 2) : 0;
    int kmax = min(46, r >> 2);
    int cntr = kmax - kmin + 1;
    int jmin = (c >= 3) ? ((c - 2) >> 1) : 0;
    int jmax = min(94, c >> 1);
    int cntc = jmax - jmin + 1;
    float invc = 1.0f / ((float)(cntr * cntc) + 1e-8f);
    sr[e] = xr[e] + pr[e] * invc;
    si[e] = xi[e] + pi[e] * invc;
}

__global__ __launch_bounds__(256) void bn_stats_kernel(
    const float* __restrict__ sr, const float* __restrict__ si,
    float* __restrict__ stats)
{
    int cc = blockIdx.x;  // 0..95 real, 96..191 imag
    const float* base = (cc < 96) ? (sr + (size_t)cc * PIX) : (si + (size_t)(cc - 96) * PIX);
    float s = 0.f, s2 = 0.f;
    for (int i = threadIdx.x; i < PIX; i += 256) {
        float v = base[i];
        s += v; s2 += v * v;
    }
    __shared__ float red[256], red2[256];
    red[threadIdx.x] = s; red2[threadIdx.x] = s2;
    __syncthreads();
    for (int off = 128; off > 0; off >>= 1) {
        if (threadIdx.x < off) {
            red[threadIdx.x]  += red[threadIdx.x + off];
            red2[threadIdx.x] += red2[threadIdx.x + off];
        }
        __syncthreads();
    }
    if (threadIdx.x == 0) {
        float mean = red[0] / (float)PIX;
        float var  = red2[0] / (float)PIX - mean * mean;
        stats[cc * 2]     = mean;
        stats[cc * 2 + 1] = rsqrtf(var + 1e-5f);
    }
}

__global__ __launch_bounds__(256) void bn_apply_kernel(
    const float* __restrict__ sr, const float* __restrict__ si,
    const float* __restrict__ gr, const float* __restrict__ br,
    const float* __restrict__ gi, const float* __restrict__ bi,
    const float* __restrict__ stats,
    float* __restrict__ outr, float* __restrict__ outi)
{
    int e = blockIdx.x * 256 + threadIdx.x;
    if (e >= 96 * PIX) return;
    int ch = e / PIX;
    float mr = stats[ch * 2],        isr = stats[ch * 2 + 1];
    float mi = stats[(96 + ch) * 2], isi = stats[(96 + ch) * 2 + 1];
    outr[e] = gr[ch] * (sr[e] - mr) * isr + br[ch];
    outi[e] = gi[ch] * (si[e] - mi) * isi + bi[ch];
}

__global__ __launch_bounds__(256) void cgelu_kernel(
    float* __restrict__ hr, float* __restrict__ hi, int n)
{
    int e = blockIdx.x * 256 + threadIdx.x;
    if (e >= n) return;
    float a = hr[e], b = hi[e];
    float mag = sqrtf(a * a + b * b);
    float ge = mag * 0.5f * (1.0f + erff(mag * 0.70710678118654752f));
    float f = ge / (mag + 1e-8f);
    hr[e] = a * f;
    hi[e] = b * f;
}

__global__ __launch_bounds__(256) void add_kernel(
    const float* __restrict__ x1r, const float* __restrict__ x1i,
    float* __restrict__ mr, float* __restrict__ mi, int n)
{
    int e = blockIdx.x * 256 + threadIdx.x;
    if (e >= n) return;
    mr[e] += x1r[e];
    mi[e] += x1i[e];
}

// ======================= launch =======================
extern "C" void kernel_launch(void* const* d_in, const int* in_sizes, int n_in,
                              void* d_out, int out_size, void* d_ws, size_t ws_size,
                              hipStream_t stream)
{
    const float* x_r     = (const float*)d_in[0];
    const float* x_i     = (const float*)d_in[1];
    const float* qkv_wr  = (const float*)d_in[2];
    const float* qkv_wi  = (const float*)d_in[3];
    const float* proj_wr = (const float*)d_in[4];
    const float* proj_wi = (const float*)d_in[5];
    const float* rel     = (const float*)d_in[6];
    const float* mlp1_wr = (const float*)d_in[7];
    const float* mlp1_wi = (const float*)d_in[8];
    const float* mlp2_wr = (const float*)d_in[9];
    const float* mlp2_wi = (const float*)d_in[10];
    const float* n1_gr   = (const float*)d_in[11];
    const float* n1_br   = (const float*)d_in[12];
    const float* n1_gi   = (const float*)d_in[13];
    const float* n1_bi   = (const float*)d_in[14];
    const float* n2_gr   = (const float*)d_in[15];
    const float* n2_br   = (const float*)d_in[16];
    const float* n2_gi   = (const float*)d_in[17];
    const float* n2_bi   = (const float*)d_in[18];

    float* ws = (float*)d_ws;
    const size_t P = PIX;
    // workspace layout (floats): total 1152*P + 384 ≈ 170 MB
    float* buf_r  = ws;                 // 384*P  (qkv 288 planes / proj 96 / mlp hidden 384)
    float* buf_i  = buf_r + 384 * P;
    float* fold_r = buf_i + 384 * P;    // 96*P  (fold -> s1 -> m -> s2)
    float* fold_i = fold_r + 96 * P;
    float* x1_r   = fold_i + 96 * P;    // 96*P  (post-BN1)
    float* x1_i   = x1_r + 96 * P;
    float* stats  = x1_i + 96 * P;      // 384

    float* out_r = (float*)d_out;
    float* out_i = out_r + 96 * P;

    dim3 blk(256);

    // 1. per-pixel QKV (avoids 4x window-overlap recompute)
    cgemm_kernel<<<dim3(576, 9), blk, 0, stream>>>(qkv_wr, qkv_wi, x_r, x_i,
                                                   buf_r, buf_i, 288, 96, PIX);
    // 2. zero fold accumulator
    hipMemsetAsync(fold_r, 0, 2 * 96 * P * sizeof(float), stream);
    // 3. attention + scatter of pre-proj outputs
    attn_kernel<<<dim3(NWIN * 6), blk, 0, stream>>>(buf_r, buf_i, rel, fold_r, fold_i);
    // 4. proj applied AFTER fold (linearity) -> reuse qkv region
    cgemm_kernel<<<dim3(576, 3), blk, 0, stream>>>(proj_wr, proj_wi, fold_r, fold_i,
                                                   buf_r, buf_i, 96, 96, PIX);
    // 5. s1 = x + proj/counts (into fold region)
    combine1_kernel<<<dim3(13824), blk, 0, stream>>>(x_r, x_i, buf_r, buf_i, fold_r, fold_i);
    // 6-7. BN1 -> x1
    bn_stats_kernel<<<dim3(192), blk, 0, stream>>>(fold_r, fold_i, stats);
    bn_apply_kernel<<<dim3(13824), blk, 0, stream>>>(fold_r, fold_i,
        n1_gr, n1_br, n1_gi, n1_bi, stats, x1_r, x1_i);
    // 8. mlp1 (96 -> 384)
    cgemm_kernel<<<dim3(576, 12), blk, 0, stream>>>(mlp1_wr, mlp1_wi, x1_r, x1_i,
                                                    buf_r, buf_i, 384, 96, PIX);
    // 9. complex-GELU in place
    cgelu_kernel<<<dim3(55296), blk, 0, stream>>>(buf_r, buf_i, 384 * PIX);
    // 10. mlp2 (384 -> 96) -> m (fold region, s1 is dead)
    cgemm_kernel<<<dim3(576, 3), blk, 0, stream>>>(mlp2_wr, mlp2_wi, buf_r, buf_i,
                                                   fold_r, fold_i, 96, 384, PIX);
    // 11. s2 = x1 + m (in place)
    add_kernel<<<dim3(13824), blk, 0, stream>>>(x1_r, x1_i, fold_r, fold_i, 96 * PIX);
    // 12-13. BN2 -> output (real plane, imag plane)
    bn_stats_kernel<<<dim3(192), blk, 0, stream>>>(fold_r, fold_i, stats);
    bn_apply_kernel<<<dim3(13824), blk, 0, stream>>>(fold_r, fold_i,
        n2_gr, n2_br, n2_gi, n2_bi, stats, out_r, out_i);
}

// Round 2
// 777.220 us; speedup vs baseline: 2.2800x; 2.2800x over previous
//
#include <hip/hip_runtime.h>
#include <math.h>

#define PIX 36864          // 192*192
#define IMW 192
#define NWIN 4465          // 47*95
#define NWIN_W 95

typedef short bf16x8 __attribute__((ext_vector_type(8)));
typedef short bf16x4 __attribute__((ext_vector_type(4)));
typedef float floatx4 __attribute__((ext_vector_type(4)));

__device__ __forceinline__ unsigned short f2bf(float f) {
    union { float f; unsigned u; } v; v.f = f;
    unsigned r = v.u + 0x7fff + ((v.u >> 16) & 1);   // RNE
    return (unsigned short)(r >> 16);
}
__device__ __forceinline__ float bf2f(unsigned short b) {
    union { unsigned u; float f; } v; v.u = ((unsigned)b) << 16;
    return v.f;
}

// ======================= weight convert: fp32 -> bf16 (+negated imag) =======================
__global__ __launch_bounds__(256) void wconv_kernel(
    const float* __restrict__ wr, const float* __restrict__ wi,
    unsigned short* __restrict__ outr, unsigned short* __restrict__ outi,
    unsigned short* __restrict__ outni, int n)
{
    int e = blockIdx.x * 256 + threadIdx.x;
    if (e >= n) return;
    outr[e] = f2bf(wr[e]);
    unsigned short b = f2bf(wi[e]);
    outi[e]  = b;
    outni[e] = b ^ 0x8000;
}

// ======================= pack: fp32 planar [k][n] -> bf16 k8-packed =======================
// dst[(k>>3)*N*8 + n*8 + (k&7)]; grid (N/256, K/8)
__global__ __launch_bounds__(256) void pack_kernel(
    const float* __restrict__ sr, const float* __restrict__ si,
    unsigned short* __restrict__ dr, unsigned short* __restrict__ di, int N)
{
    int n  = blockIdx.x * 256 + threadIdx.x;
    int kb = blockIdx.y;
    bf16x8 vr, vi;
#pragma unroll
    for (int j = 0; j < 8; ++j) {
        ((unsigned short*)&vr)[j] = f2bf(sr[(size_t)(kb * 8 + j) * N + n]);
        ((unsigned short*)&vi)[j] = f2bf(si[(size_t)(kb * 8 + j) * N + n]);
    }
    *(bf16x8*)&dr[((size_t)kb * N + n) * 8] = vr;
    *(bf16x8*)&di[((size_t)kb * N + n) * 8] = vi;
}

// ======================= complex GEMM via MFMA =======================
// Y = W * X (complex), W: M x K row-major bf16 (r / i / -i copies),
// X: k8-packed bf16 per component. Block: 256 thr = 4 waves, tile BM=32 x BN=256
// (wave = 32x64). No LDS. STORE_PACKED=1 writes Y in k8-packed bf16 instead of fp32 planar.
template<int K, int STORE_PACKED>
__global__ __launch_bounds__(256, 2) void cgemm_mfma_kernel(
    const unsigned short* __restrict__ Wr, const unsigned short* __restrict__ Wi,
    const unsigned short* __restrict__ Wni,
    const unsigned short* __restrict__ Xr, const unsigned short* __restrict__ Xi,
    float* __restrict__ Yr, float* __restrict__ Yi,
    unsigned short* __restrict__ Pr, unsigned short* __restrict__ Pi,
    int N)
{
    const int lane = threadIdx.x & 63;
    const int wave = threadIdx.x >> 6;
    const int g = lane >> 4;     // k-group (0..3)
    const int r = lane & 15;     // row (A) / col (B)
    const int m0 = blockIdx.x * 32;
    const int n0 = blockIdx.y * 256 + wave * 64;

    floatx4 accR[2][4], accI[2][4];
#pragma unroll
    for (int t = 0; t < 2; ++t)
#pragma unroll
        for (int j = 0; j < 4; ++j) {
            accR[t][j] = (floatx4){0.f, 0.f, 0.f, 0.f};
            accI[t][j] = (floatx4){0.f, 0.f, 0.f, 0.f};
        }

    for (int kc = 0; kc < K; kc += 32) {
        bf16x8 awr[2], awi[2], awni[2];
#pragma unroll
        for (int t = 0; t < 2; ++t) {
            size_t wb = (size_t)(m0 + t * 16 + r) * K + kc + g * 8;
            awr[t]  = *(const bf16x8*)&Wr[wb];
            awi[t]  = *(const bf16x8*)&Wi[wb];
            awni[t] = *(const bf16x8*)&Wni[wb];
        }
        bf16x8 bxr[4], bxi[4];
        const size_t krow = (size_t)((kc >> 3) + g);
#pragma unroll
        for (int j = 0; j < 4; ++j) {
            size_t off = (krow * N + n0 + j * 16 + r) * 8;
            bxr[j] = *(const bf16x8*)&Xr[off];
            bxi[j] = *(const bf16x8*)&Xi[off];
        }
#pragma unroll
        for (int t = 0; t < 2; ++t)
#pragma unroll
            for (int j = 0; j < 4; ++j) {
                accR[t][j] = __builtin_amdgcn_mfma_f32_16x16x32_bf16(awr[t],  bxr[j], accR[t][j], 0, 0, 0);
                accR[t][j] = __builtin_amdgcn_mfma_f32_16x16x32_bf16(awni[t], bxi[j], accR[t][j], 0, 0, 0);
                accI[t][j] = __builtin_amdgcn_mfma_f32_16x16x32_bf16(awr[t],  bxi[j], accI[t][j], 0, 0, 0);
                accI[t][j] = __builtin_amdgcn_mfma_f32_16x16x32_bf16(awi[t],  bxr[j], accI[t][j], 0, 0, 0);
            }
    }

    if (!STORE_PACKED) {
#pragma unroll
        for (int t = 0; t < 2; ++t)
#pragma unroll
            for (int j = 0; j < 4; ++j) {
                int col = n0 + j * 16 + r;
#pragma unroll
                for (int reg = 0; reg < 4; ++reg) {
                    int row = m0 + t * 16 + g * 4 + reg;   // C layout: col=lane&15, row=(lane>>4)*4+reg
                    Yr[(size_t)row * N + col] = accR[t][j][reg];
                    Yi[(size_t)row * N + col] = accI[t][j][reg];
                }
            }
    } else {
#pragma unroll
        for (int t = 0; t < 2; ++t)
#pragma unroll
            for (int j = 0; j < 4; ++j) {
                int col = n0 + j * 16 + r;
                size_t rowblk = (size_t)((m0 + t * 16 + g * 4) >> 3);
                int sub = (g & 1) * 4;
                bf16x4 pr, pi;
#pragma unroll
                for (int reg = 0; reg < 4; ++reg) {
                    ((unsigned short*)&pr)[reg] = f2bf(accR[t][j][reg]);
                    ((unsigned short*)&pi)[reg] = f2bf(accI[t][j][reg]);
                }
                *(bf16x4*)&Pr[(rowblk * N + col) * 8 + sub] = pr;
                *(bf16x4*)&Pi[(rowblk * N + col) * 8 + sub] = pi;
            }
    }
}

// ======================= attention per (window, head) =======================
__global__ __launch_bounds__(256) void attn_kernel(
    const float* __restrict__ qkv_r, const float* __restrict__ qkv_i,
    const float* __restrict__ rel,
    float* __restrict__ fold_r, float* __restrict__ fold_i)
{
    const int blk = blockIdx.x;
    const int h  = blk % 6;
    const int w  = blk / 6;
    const int nh = w / NWIN_W;
    const int nw = w % NWIN_W;
    const int r0 = nh * 4, c0 = nw * 2;

    __shared__ float sQ[2][16][36];
    __shared__ float sK[2][16][36];
    __shared__ float sV[2][16][36];
    __shared__ float sA[2][32][36];

    const int tid = threadIdx.x;

#pragma unroll
    for (int j = 0; j < 12; ++j) {
        int e = tid + j * 256;
        int mat   = e >> 9;
        int idx   = e & 511;
        int d     = idx >> 5;
        int p     = idx & 31;
        int comp  = mat & 1;
        int which = mat >> 1;
        int ch = which * 96 + h * 16 + d;
        const float* src = comp ? qkv_i : qkv_r;
        float val = src[(size_t)ch * PIX + (size_t)(r0 + (p >> 2)) * IMW + c0 + (p & 3)];
        if (which == 0)      sQ[comp][d][p] = val;
        else if (which == 1) sK[comp][d][p] = val;
        else                 sV[comp][d][p] = val;
    }
    __syncthreads();

    const int n  = tid >> 3;
    const int mb = (tid & 7) * 4;
    float ar[4] = {0.f,0.f,0.f,0.f}, ai[4] = {0.f,0.f,0.f,0.f};
#pragma unroll
    for (int d = 0; d < 16; ++d) {
        float qr = sQ[0][d][n], qi = sQ[1][d][n];
        const float4 kr4 = *(const float4*)&sK[0][d][mb];
        const float4 ki4 = *(const float4*)&sK[1][d][mb];
        const float krv[4] = {kr4.x, kr4.y, kr4.z, kr4.w};
        const float kiv[4] = {ki4.x, ki4.y, ki4.z, ki4.w};
#pragma unroll
        for (int jj = 0; jj < 4; ++jj) {
            ar[jj] += qr * krv[jj] + qi * kiv[jj];
            ai[jj] += qi * krv[jj] - qr * kiv[jj];
        }
    }
    const int yn = n >> 2, xn = n & 3;
    float mag[4];
#pragma unroll
    for (int jj = 0; jj < 4; ++jj) {
        int m = mb + jj;
        int ym = m >> 2, xm = m & 3;
        int ridx = (yn - ym + 7) * 7 + (xn - xm + 3);
        ar[jj] = ar[jj] * 0.25f + rel[h * 105 + ridx];
        ai[jj] *= 0.25f;
        mag[jj] = sqrtf(ar[jj]*ar[jj] + ai[jj]*ai[jj]);
    }
    float mx = fmaxf(fmaxf(mag[0], mag[1]), fmaxf(mag[2], mag[3]));
#pragma unroll
    for (int off = 1; off < 8; off <<= 1)
        mx = fmaxf(mx, __shfl_xor(mx, off, 64));
    float es[4], ssum = 0.f;
#pragma unroll
    for (int jj = 0; jj < 4; ++jj) { es[jj] = expf(mag[jj] - mx); ssum += es[jj]; }
#pragma unroll
    for (int off = 1; off < 8; off <<= 1)
        ssum += __shfl_xor(ssum, off, 64);
    const float inv = 1.0f / ssum;
#pragma unroll
    for (int jj = 0; jj < 4; ++jj) {
        float f = es[jj] * inv / (mag[jj] + 1e-8f);
        sA[0][n][mb + jj] = ar[jj] * f;
        sA[1][n][mb + jj] = ai[jj] * f;
    }
    __syncthreads();

    const int dd = tid & 15;
    const int n1 = tid >> 4;
    const int n2 = n1 + 16;
    float o1r = 0.f, o1i = 0.f, o2r = 0.f, o2i = 0.f;
#pragma unroll
    for (int m = 0; m < 32; ++m) {
        float vr = sV[0][dd][m], vi = sV[1][dd][m];
        float a1r = sA[0][n1][m], a1i = sA[1][n1][m];
        float a2r = sA[0][n2][m], a2i = sA[1][n2][m];
        o1r += a1r * vr - a1i * vi;  o1i += a1r * vi + a1i * vr;
        o2r += a2r * vr - a2i * vi;  o2i += a2r * vi + a2i * vr;
    }
    const int ch = h * 16 + dd;
    size_t base = (size_t)ch * PIX;
    int g1 = (r0 + (n1 >> 2)) * IMW + c0 + (n1 & 3);
    int g2 = (r0 + (n2 >> 2)) * IMW + c0 + (n2 & 3);
    atomicAdd(&fold_r[base + g1], o1r);
    atomicAdd(&fold_i[base + g1], o1i);
    atomicAdd(&fold_r[base + g2], o2r);
    atomicAdd(&fold_i[base + g2], o2i);
}

// ======================= elementwise / BN =======================
__global__ __launch_bounds__(256) void combine1_kernel(
    const float* __restrict__ xr, const float* __restrict__ xi,
    const float* __restrict__ pr, const float* __restrict__ pi,
    float* __restrict__ sr, float* __restrict__ si)
{
    int e = blockIdx.x * 256 + threadIdx.x;
    if (e >= 96 * PIX) return;
    int g = e % PIX;
    int r = g / IMW, c = g % IMW;
    int kmin = (r >= 7) ? ((r - 4) >> 2) : 0;
    int kmax = min(46, r >> 2);
    int cntr = kmax - kmin + 1;
    int jmin = (c >= 3) ? ((c - 2) >> 1) : 0;
    int jmax = min(94, c >> 1);
    int cntc = jmax - jmin + 1;
    float invc = 1.0f / ((float)(cntr * cntc) + 1e-8f);
    sr[e] = xr[e] + pr[e] * invc;
    si[e] = xi[e] + pi[e] * invc;
}

__global__ __launch_bounds__(256) void bn_stats_kernel(
    const float* __restrict__ sr, const float* __restrict__ si,
    float* __restrict__ stats)
{
    int cc = blockIdx.x;
    const float* base = (cc < 96) ? (sr + (size_t)cc * PIX) : (si + (size_t)(cc - 96) * PIX);
    float s = 0.f, s2 = 0.f;
    for (int i = threadIdx.x; i < PIX; i += 256) {
        float v = base[i];
        s += v; s2 += v * v;
    }
    __shared__ float red[256], red2[256];
    red[threadIdx.x] = s; red2[threadIdx.x] = s2;
    __syncthreads();
    for (int off = 128; off > 0; off >>= 1) {
        if (threadIdx.x < off) {
            red[threadIdx.x]  += red[threadIdx.x + off];
            red2[threadIdx.x] += red2[threadIdx.x + off];
        }
        __syncthreads();
    }
    if (threadIdx.x == 0) {
        float mean = red[0] / (float)PIX;
        float var  = red2[0] / (float)PIX - mean * mean;
        stats[cc * 2]     = mean;
        stats[cc * 2 + 1] = rsqrtf(var + 1e-5f);
    }
}

__global__ __launch_bounds__(256) void bn_apply_kernel(
    const float* __restrict__ sr, const float* __restrict__ si,
    const float* __restrict__ gr, const float* __restrict__ br,
    const float* __restrict__ gi, const float* __restrict__ bi,
    const float* __restrict__ stats,
    float* __restrict__ outr, float* __restrict__ outi)
{
    int e = blockIdx.x * 256 + threadIdx.x;
    if (e >= 96 * PIX) return;
    int ch = e / PIX;
    float mr = stats[ch * 2],        isr = stats[ch * 2 + 1];
    float mi = stats[(96 + ch) * 2], isi = stats[(96 + ch) * 2 + 1];
    outr[e] = gr[ch] * (sr[e] - mr) * isr + br[ch];
    outi[e] = gi[ch] * (si[e] - mi) * isi + bi[ch];
}

// cgelu on the bf16 k8-packed mlp hidden buffer, in place
__global__ __launch_bounds__(256) void cgelu_pack_kernel(
    unsigned short* __restrict__ hr, unsigned short* __restrict__ hi)
{
    size_t e = ((size_t)blockIdx.x * 256 + threadIdx.x) * 8;
    bf16x8 vr = *(bf16x8*)&hr[e];
    bf16x8 vi = *(bf16x8*)&hi[e];
#pragma unroll
    for (int j = 0; j < 8; ++j) {
        float a = bf2f(((unsigned short*)&vr)[j]);
        float b = bf2f(((unsigned short*)&vi)[j]);
        float mag = sqrtf(a * a + b * b);
        float ge = mag * 0.5f * (1.0f + erff(mag * 0.70710678118654752f));
        float f = ge / (mag + 1e-8f);
        ((unsigned short*)&vr)[j] = f2bf(a * f);
        ((unsigned short*)&vi)[j] = f2bf(b * f);
    }
    *(bf16x8*)&hr[e] = vr;
    *(bf16x8*)&hi[e] = vi;
}

__global__ __launch_bounds__(256) void add_kernel(
    const float* __restrict__ x1r, const float* __restrict__ x1i,
    float* __restrict__ mr, float* __restrict__ mi, int n)
{
    int e = blockIdx.x * 256 + threadIdx.x;
    if (e >= n) return;
    mr[e] += x1r[e];
    mi[e] += x1i[e];
}

// ======================= launch =======================
extern "C" void kernel_launch(void* const* d_in, const int* in_sizes, int n_in,
                              void* d_out, int out_size, void* d_ws, size_t ws_size,
                              hipStream_t stream)
{
    const float* x_r     = (const float*)d_in[0];
    const float* x_i     = (const float*)d_in[1];
    const float* qkv_wr  = (const float*)d_in[2];
    const float* qkv_wi  = (const float*)d_in[3];
    const float* proj_wr = (const float*)d_in[4];
    const float* proj_wi = (const float*)d_in[5];
    const float* rel     = (const float*)d_in[6];
    const float* mlp1_wr = (const float*)d_in[7];
    const float* mlp1_wi = (const float*)d_in[8];
    const float* mlp2_wr = (const float*)d_in[9];
    const float* mlp2_wi = (const float*)d_in[10];
    const float* n1_gr   = (const float*)d_in[11];
    const float* n1_br   = (const float*)d_in[12];
    const float* n1_gi   = (const float*)d_in[13];
    const float* n1_bi   = (const float*)d_in[14];
    const float* n2_gr   = (const float*)d_in[15];
    const float* n2_br   = (const float*)d_in[16];
    const float* n2_gi   = (const float*)d_in[17];
    const float* n2_bi   = (const float*)d_in[18];

    const size_t P = PIX;
    float* ws = (float*)d_ws;
    // region A: fp32 GEMM outputs (qkv 288x2 / proj 96x2); also reused (as ushort) for packed mlp hidden
    float* A  = ws;                         // 2*288*P floats
    float* B_ = A  + 2 * 288 * P;           // fold / s1 / m : 2*96*P
    float* C_ = B_ + 2 * 96 * P;            // x1 : 2*96*P
    unsigned short* D = (unsigned short*)(C_ + 2 * 96 * P);  // packed small: 2*96*P ushorts
    unsigned short* Wb = (unsigned short*)((float*)D + 96 * P);  // weights bf16: 331776 ushorts
    float* stats = (float*)Wb + 165888 / 1 * 0 + 0;  // placed after weights:
    stats = (float*)(Wb + 331776);

    // weight sub-buffers (bf16): r, i, -i per matrix
    unsigned short* wq_r  = Wb;            unsigned short* wq_i  = Wb + 27648;  unsigned short* wq_ni = Wb + 55296;
    unsigned short* wp_r  = Wb + 82944;    unsigned short* wp_i  = Wb + 92160;  unsigned short* wp_ni = Wb + 101376;
    unsigned short* w1_r  = Wb + 110592;   unsigned short* w1_i  = Wb + 147456; unsigned short* w1_ni = Wb + 184320;
    unsigned short* w2_r  = Wb + 221184;   unsigned short* w2_i  = Wb + 258048; unsigned short* w2_ni = Wb + 294912;

    unsigned short* Dr = D;
    unsigned short* Di = D + 96 * P;
    unsigned short* hb_r = (unsigned short*)A;          // packed mlp hidden (384 planes/comp)
    unsigned short* hb_i = hb_r + 384 * P;

    float* out_r = (float*)d_out;
    float* out_i = out_r + 96 * P;

    dim3 blk(256);

    // 0. weights -> bf16 (+ negated imag)
    wconv_kernel<<<dim3(108), blk, 0, stream>>>(qkv_wr, qkv_wi, wq_r, wq_i, wq_ni, 27648);
    wconv_kernel<<<dim3(36),  blk, 0, stream>>>(proj_wr, proj_wi, wp_r, wp_i, wp_ni, 9216);
    wconv_kernel<<<dim3(144), blk, 0, stream>>>(mlp1_wr, mlp1_wi, w1_r, w1_i, w1_ni, 36864);
    wconv_kernel<<<dim3(144), blk, 0, stream>>>(mlp2_wr, mlp2_wi, w2_r, w2_i, w2_ni, 36864);

    // 1. pack x -> bf16 k8
    pack_kernel<<<dim3(144, 12), blk, 0, stream>>>(x_r, x_i, Dr, Di, PIX);
    // 2. QKV gemm (M=288, K=96) -> fp32 planar in A
    cgemm_mfma_kernel<96, 0><<<dim3(9, 144), blk, 0, stream>>>(
        wq_r, wq_i, wq_ni, Dr, Di, A, A + 288 * P, nullptr, nullptr, PIX);
    // 3. zero fold, attention scatter (pre-proj, fold commutes with proj)
    hipMemsetAsync(B_, 0, 2 * 96 * P * sizeof(float), stream);
    attn_kernel<<<dim3(NWIN * 6), blk, 0, stream>>>(A, A + 288 * P, rel, B_, B_ + 96 * P);
    // 4. pack fold, proj gemm (M=96, K=96) -> A
    pack_kernel<<<dim3(144, 12), blk, 0, stream>>>(B_, B_ + 96 * P, Dr, Di, PIX);
    cgemm_mfma_kernel<96, 0><<<dim3(3, 144), blk, 0, stream>>>(
        wp_r, wp_i, wp_ni, Dr, Di, A, A + 96 * P, nullptr, nullptr, PIX);
    // 5. s1 = x + proj/counts -> B
    combine1_kernel<<<dim3(13824), blk, 0, stream>>>(x_r, x_i, A, A + 96 * P, B_, B_ + 96 * P);
    // 6. BN1 -> x1 (C)
    bn_stats_kernel<<<dim3(192), blk, 0, stream>>>(B_, B_ + 96 * P, stats);
    bn_apply_kernel<<<dim3(13824), blk, 0, stream>>>(B_, B_ + 96 * P,
        n1_gr, n1_br, n1_gi, n1_bi, stats, C_, C_ + 96 * P);
    // 7. pack x1, mlp1 gemm (M=384, K=96) -> packed bf16 hidden (A region)
    pack_kernel<<<dim3(144, 12), blk, 0, stream>>>(C_, C_ + 96 * P, Dr, Di, PIX);
    cgemm_mfma_kernel<96, 1><<<dim3(12, 144), blk, 0, stream>>>(
        w1_r, w1_i, w1_ni, Dr, Di, nullptr, nullptr, hb_r, hb_i, PIX);
    // 8. cgelu in place on packed hidden
    cgelu_pack_kernel<<<dim3(6912), blk, 0, stream>>>(hb_r, hb_i);
    // 9. mlp2 gemm (M=96, K=384) -> m (B)
    cgemm_mfma_kernel<384, 0><<<dim3(3, 144), blk, 0, stream>>>(
        w2_r, w2_i, w2_ni, hb_r, hb_i, B_, B_ + 96 * P, nullptr, nullptr, PIX);
    // 10. s2 = x1 + m
    add_kernel<<<dim3(13824), blk, 0, stream>>>(C_, C_ + 96 * P, B_, B_ + 96 * P, 96 * PIX);
    // 11. BN2 -> out
    bn_stats_kernel<<<dim3(192), blk, 0, stream>>>(B_, B_ + 96 * P, stats);
    bn_apply_kernel<<<dim3(13824), blk, 0, stream>>>(B_, B_ + 96 * P,
        n2_gr, n2_br, n2_gi, n2_bi, stats, out_r, out_i);
}

// Round 3
// 659.667 us; speedup vs baseline: 2.6864x; 1.1782x over previous
//
#include <hip/hip_runtime.h>
#include <math.h>

#define PIX 36864          // 192*192
#define IMW 192
#define NWIN 4465          // 47*95
#define NWIN_W 95

typedef short bf16x8 __attribute__((ext_vector_type(8)));
typedef short bf16x4 __attribute__((ext_vector_type(4)));
typedef float floatx4 __attribute__((ext_vector_type(4)));

__device__ __forceinline__ unsigned short f2bf(float f) {
    union { float f; unsigned u; } v; v.f = f;
    unsigned r = v.u + 0x7fff + ((v.u >> 16) & 1);   // RNE
    return (unsigned short)(r >> 16);
}
__device__ __forceinline__ float bf2f(unsigned short b) {
    union { unsigned u; float f; } v; v.u = ((unsigned)b) << 16;
    return v.f;
}

// ======================= weight convert: fp32 -> bf16 (+negated imag) =======================
__global__ __launch_bounds__(256) void wconv_kernel(
    const float* __restrict__ wr, const float* __restrict__ wi,
    unsigned short* __restrict__ outr, unsigned short* __restrict__ outi,
    unsigned short* __restrict__ outni, int n)
{
    int e = blockIdx.x * 256 + threadIdx.x;
    if (e >= n) return;
    outr[e] = f2bf(wr[e]);
    unsigned short b = f2bf(wi[e]);
    outi[e]  = b;
    outni[e] = b ^ 0x8000;
}

// ======================= pack: fp32 planar [k][n] -> bf16 k8-packed =======================
// dst[(k>>3)*N*8 + n*8 + (k&7)]; grid (N/256, K/8)
__global__ __launch_bounds__(256) void pack_kernel(
    const float* __restrict__ sr, const float* __restrict__ si,
    unsigned short* __restrict__ dr, unsigned short* __restrict__ di, int N)
{
    int n  = blockIdx.x * 256 + threadIdx.x;
    int kb = blockIdx.y;
    bf16x8 vr, vi;
#pragma unroll
    for (int j = 0; j < 8; ++j) {
        ((unsigned short*)&vr)[j] = f2bf(sr[(size_t)(kb * 8 + j) * N + n]);
        ((unsigned short*)&vi)[j] = f2bf(si[(size_t)(kb * 8 + j) * N + n]);
    }
    *(bf16x8*)&dr[((size_t)kb * N + n) * 8] = vr;
    *(bf16x8*)&di[((size_t)kb * N + n) * 8] = vi;
}

// pack + BN1 apply fused: reads s1 fp32 planar, writes packed bf16 x1
__global__ __launch_bounds__(256) void pack_bn_kernel(
    const float* __restrict__ sr, const float* __restrict__ si,
    const float* __restrict__ stats,
    const float* __restrict__ gr, const float* __restrict__ br,
    const float* __restrict__ gi, const float* __restrict__ bi,
    unsigned short* __restrict__ dr, unsigned short* __restrict__ di, int N)
{
    int n  = blockIdx.x * 256 + threadIdx.x;
    int kb = blockIdx.y;
    bf16x8 vr, vi;
#pragma unroll
    for (int j = 0; j < 8; ++j) {
        int ch = kb * 8 + j;
        float mr = stats[ch * 2],        isr = stats[ch * 2 + 1];
        float mi = stats[(96 + ch) * 2], isi = stats[(96 + ch) * 2 + 1];
        ((unsigned short*)&vr)[j] = f2bf(gr[ch] * (sr[(size_t)ch * N + n] - mr) * isr + br[ch]);
        ((unsigned short*)&vi)[j] = f2bf(gi[ch] * (si[(size_t)ch * N + n] - mi) * isi + bi[ch]);
    }
    *(bf16x8*)&dr[((size_t)kb * N + n) * 8] = vr;
    *(bf16x8*)&di[((size_t)kb * N + n) * 8] = vi;
}

// ======================= complex GEMM via MFMA =======================
// Y = W * X (complex), W: M x K row-major bf16 (r / i / -i copies),
// X: k8-packed bf16 per component. Block: 256 thr = 4 waves, tile BM=32 x BN=256.
// STORE: 0 = fp32 planar (Yr/Yi), 1 = k8-packed bf16 (Pr/Pi),
//        2 = pixel-major interleaved bf16 qkvb[pix][which][head][d][comp] (Pr)
template<int K, int STORE>
__global__ __launch_bounds__(256, 2) void cgemm_mfma_kernel(
    const unsigned short* __restrict__ Wr, const unsigned short* __restrict__ Wi,
    const unsigned short* __restrict__ Wni,
    const unsigned short* __restrict__ Xr, const unsigned short* __restrict__ Xi,
    float* __restrict__ Yr, float* __restrict__ Yi,
    unsigned short* __restrict__ Pr, unsigned short* __restrict__ Pi,
    int N)
{
    const int lane = threadIdx.x & 63;
    const int wave = threadIdx.x >> 6;
    const int g = lane >> 4;     // k-group (0..3)
    const int r = lane & 15;     // row (A) / col (B)
    const int m0 = blockIdx.x * 32;
    const int n0 = blockIdx.y * 256 + wave * 64;

    floatx4 accR[2][4], accI[2][4];
#pragma unroll
    for (int t = 0; t < 2; ++t)
#pragma unroll
        for (int j = 0; j < 4; ++j) {
            accR[t][j] = (floatx4){0.f, 0.f, 0.f, 0.f};
            accI[t][j] = (floatx4){0.f, 0.f, 0.f, 0.f};
        }

    for (int kc = 0; kc < K; kc += 32) {
        bf16x8 awr[2], awi[2], awni[2];
#pragma unroll
        for (int t = 0; t < 2; ++t) {
            size_t wb = (size_t)(m0 + t * 16 + r) * K + kc + g * 8;
            awr[t]  = *(const bf16x8*)&Wr[wb];
            awi[t]  = *(const bf16x8*)&Wi[wb];
            awni[t] = *(const bf16x8*)&Wni[wb];
        }
        bf16x8 bxr[4], bxi[4];
        const size_t krow = (size_t)((kc >> 3) + g);
#pragma unroll
        for (int j = 0; j < 4; ++j) {
            size_t off = (krow * N + n0 + j * 16 + r) * 8;
            bxr[j] = *(const bf16x8*)&Xr[off];
            bxi[j] = *(const bf16x8*)&Xi[off];
        }
#pragma unroll
        for (int t = 0; t < 2; ++t)
#pragma unroll
            for (int j = 0; j < 4; ++j) {
                accR[t][j] = __builtin_amdgcn_mfma_f32_16x16x32_bf16(awr[t],  bxr[j], accR[t][j], 0, 0, 0);
                accR[t][j] = __builtin_amdgcn_mfma_f32_16x16x32_bf16(awni[t], bxi[j], accR[t][j], 0, 0, 0);
                accI[t][j] = __builtin_amdgcn_mfma_f32_16x16x32_bf16(awr[t],  bxi[j], accI[t][j], 0, 0, 0);
                accI[t][j] = __builtin_amdgcn_mfma_f32_16x16x32_bf16(awi[t],  bxr[j], accI[t][j], 0, 0, 0);
            }
    }

    if (STORE == 0) {
#pragma unroll
        for (int t = 0; t < 2; ++t)
#pragma unroll
            for (int j = 0; j < 4; ++j) {
                int col = n0 + j * 16 + r;
#pragma unroll
                for (int reg = 0; reg < 4; ++reg) {
                    int row = m0 + t * 16 + g * 4 + reg;   // C layout: col=lane&15, row=(lane>>4)*4+reg
                    Yr[(size_t)row * N + col] = accR[t][j][reg];
                    Yi[(size_t)row * N + col] = accI[t][j][reg];
                }
            }
    } else if (STORE == 1) {
#pragma unroll
        for (int t = 0; t < 2; ++t)
#pragma unroll
            for (int j = 0; j < 4; ++j) {
                int col = n0 + j * 16 + r;
                size_t rowblk = (size_t)((m0 + t * 16 + g * 4) >> 3);
                int sub = (g & 1) * 4;
                bf16x4 pr, pi;
#pragma unroll
                for (int reg = 0; reg < 4; ++reg) {
                    ((unsigned short*)&pr)[reg] = f2bf(accR[t][j][reg]);
                    ((unsigned short*)&pi)[reg] = f2bf(accI[t][j][reg]);
                }
                *(bf16x4*)&Pr[(rowblk * N + col) * 8 + sub] = pr;
                *(bf16x4*)&Pi[(rowblk * N + col) * 8 + sub] = pi;
            }
    } else {
        // qkvb: per (pix, which, head) slot of 32 ushorts = [d 0..15][re,im]
#pragma unroll
        for (int t = 0; t < 2; ++t) {
            int ch0 = m0 + t * 16;
            int which = ch0 / 96;
            int hh = (ch0 % 96) / 16;
#pragma unroll
            for (int j = 0; j < 4; ++j) {
                int col = n0 + j * 16 + r;      // pixel
                bf16x8 pk;
#pragma unroll
                for (int reg = 0; reg < 4; ++reg) {
                    ((unsigned short*)&pk)[reg * 2]     = f2bf(accR[t][j][reg]);
                    ((unsigned short*)&pk)[reg * 2 + 1] = f2bf(accI[t][j][reg]);
                }
                *(bf16x8*)&Pr[(((size_t)col * 3 + which) * 6 + hh) * 32 + g * 8] = pk;
            }
        }
    }
}

// ======================= attention per (window, head) =======================
// Reads pixel-major qkvb, computes magnitude-softmax attention, writes per-window
// bf16 output wout[win][pix][ch][comp] (no atomics).
__global__ __launch_bounds__(256) void attn_kernel(
    const unsigned short* __restrict__ qkvb,
    const float* __restrict__ rel,
    unsigned short* __restrict__ wout)
{
    const int blk = blockIdx.x;
    const int h  = blk % 6;
    const int w  = blk / 6;
    const int nh = w / NWIN_W;
    const int nw = w % NWIN_W;
    const int r0 = nh * 4, c0 = nw * 2;

    __shared__ float sQ[2][16][36];
    __shared__ float sK[2][16][36];
    __shared__ float sV[2][16][36];
    __shared__ float sA[2][32][36];

    const int tid = threadIdx.x;

    // stage: 32 pix x 3 tensors x 8 chunks(8B) = 768 chunks
#pragma unroll
    for (int j = 0; j < 3; ++j) {
        int c = tid + j * 256;
        int pix  = c / 24;
        int rest = c % 24;
        int which = rest >> 3;
        int part  = rest & 7;
        int gpix = (r0 + (pix >> 2)) * IMW + c0 + (pix & 3);
        const ushort4 u = *(const ushort4*)&qkvb[(((size_t)gpix * 3 + which) * 6 + h) * 32 + part * 4];
        float v0 = bf2f(u.x), v1 = bf2f(u.y), v2 = bf2f(u.z), v3 = bf2f(u.w);
        int d0 = part * 2;
        if (which == 0)      { sQ[0][d0][pix] = v0; sQ[1][d0][pix] = v1; sQ[0][d0+1][pix] = v2; sQ[1][d0+1][pix] = v3; }
        else if (which == 1) { sK[0][d0][pix] = v0; sK[1][d0][pix] = v1; sK[0][d0+1][pix] = v2; sK[1][d0+1][pix] = v3; }
        else                 { sV[0][d0][pix] = v0; sV[1][d0][pix] = v1; sV[0][d0+1][pix] = v2; sV[1][d0+1][pix] = v3; }
    }
    __syncthreads();

    const int n  = tid >> 3;
    const int mb = (tid & 7) * 4;
    float ar[4] = {0.f,0.f,0.f,0.f}, ai[4] = {0.f,0.f,0.f,0.f};
#pragma unroll
    for (int d = 0; d < 16; ++d) {
        float qr = sQ[0][d][n], qi = sQ[1][d][n];
        const float4 kr4 = *(const float4*)&sK[0][d][mb];
        const float4 ki4 = *(const float4*)&sK[1][d][mb];
        const float krv[4] = {kr4.x, kr4.y, kr4.z, kr4.w};
        const float kiv[4] = {ki4.x, ki4.y, ki4.z, ki4.w};
#pragma unroll
        for (int jj = 0; jj < 4; ++jj) {
            ar[jj] += qr * krv[jj] + qi * kiv[jj];   // q * conj(k)
            ai[jj] += qi * krv[jj] - qr * kiv[jj];
        }
    }
    const int yn = n >> 2, xn = n & 3;
    float mag[4];
#pragma unroll
    for (int jj = 0; jj < 4; ++jj) {
        int m = mb + jj;
        int ym = m >> 2, xm = m & 3;
        int ridx = (yn - ym + 7) * 7 + (xn - xm + 3);
        ar[jj] = ar[jj] * 0.25f + rel[h * 105 + ridx];
        ai[jj] *= 0.25f;
        mag[jj] = sqrtf(ar[jj]*ar[jj] + ai[jj]*ai[jj]);
    }
    float mx = fmaxf(fmaxf(mag[0], mag[1]), fmaxf(mag[2], mag[3]));
#pragma unroll
    for (int off = 1; off < 8; off <<= 1)
        mx = fmaxf(mx, __shfl_xor(mx, off, 64));
    float es[4], ssum = 0.f;
#pragma unroll
    for (int jj = 0; jj < 4; ++jj) { es[jj] = expf(mag[jj] - mx); ssum += es[jj]; }
#pragma unroll
    for (int off = 1; off < 8; off <<= 1)
        ssum += __shfl_xor(ssum, off, 64);
    const float inv = 1.0f / ssum;
#pragma unroll
    for (int jj = 0; jj < 4; ++jj) {
        float f = es[jj] * inv / (mag[jj] + 1e-8f);
        sA[0][n][mb + jj] = ar[jj] * f;
        sA[1][n][mb + jj] = ai[jj] * f;
    }
    __syncthreads();

    const int dd = tid & 15;
    const int n1 = tid >> 4;
    const int n2 = n1 + 16;
    float o1r = 0.f, o1i = 0.f, o2r = 0.f, o2i = 0.f;
#pragma unroll
    for (int m = 0; m < 32; ++m) {
        float vr = sV[0][dd][m], vi = sV[1][dd][m];
        float a1r = sA[0][n1][m], a1i = sA[1][n1][m];
        float a2r = sA[0][n2][m], a2i = sA[1][n2][m];
        o1r += a1r * vr - a1i * vi;  o1i += a1r * vi + a1i * vr;
        o2r += a2r * vr - a2i * vi;  o2i += a2r * vi + a2i * vr;
    }
    const int ch = h * 16 + dd;
    ushort2 s1v; s1v.x = f2bf(o1r); s1v.y = f2bf(o1i);
    ushort2 s2v; s2v.x = f2bf(o2r); s2v.y = f2bf(o2i);
    *(ushort2*)&wout[(((size_t)w * 32 + n1) * 96 + ch) * 2] = s1v;
    *(ushort2*)&wout[(((size_t)w * 32 + n2) * 96 + ch) * 2] = s2v;
}

// ======================= fold + count-div + pack for proj =======================
// Per pixel, sum <=4 window contributions, divide by (cnt+eps), write packed bf16.
__global__ __launch_bounds__(256) void fold_pack_kernel(
    const unsigned short* __restrict__ wout,
    unsigned short* __restrict__ dr, unsigned short* __restrict__ di)
{
    int e = blockIdx.x * 256 + threadIdx.x;   // PIX*12
    int gpix = e / 12;
    int kb   = e % 12;
    int r = gpix / IMW, c = gpix % IMW;
    int nh0 = (r >= 7) ? ((r - 4) >> 2) : 0;
    int nh1 = min(46, r >> 2);
    int nw0 = (c >= 3) ? ((c - 2) >> 1) : 0;
    int nw1 = min(94, c >> 1);

    float accr[8] = {0,0,0,0,0,0,0,0}, acci[8] = {0,0,0,0,0,0,0,0};
    int cnt = 0;
    for (int nh = nh0; nh <= nh1; ++nh)
        for (int nw = nw0; nw <= nw1; ++nw) {
            int win = nh * NWIN_W + nw;
            int n = (r - nh * 4) * 4 + (c - nw * 2);
            const unsigned short* src = &wout[(((size_t)win * 32 + n) * 96 + kb * 8) * 2];
            bf16x8 a = *(const bf16x8*)&src[0];
            bf16x8 b = *(const bf16x8*)&src[8];
#pragma unroll
            for (int j = 0; j < 4; ++j) {
                accr[j]     += bf2f((unsigned short)a[j*2]);
                acci[j]     += bf2f((unsigned short)a[j*2+1]);
                accr[4 + j] += bf2f((unsigned short)b[j*2]);
                acci[4 + j] += bf2f((unsigned short)b[j*2+1]);
            }
            ++cnt;
        }
    float invc = 1.0f / ((float)cnt + 1e-8f);
    bf16x8 pr, pi;
#pragma unroll
    for (int j = 0; j < 8; ++j) {
        ((unsigned short*)&pr)[j] = f2bf(accr[j] * invc);
        ((unsigned short*)&pi)[j] = f2bf(acci[j] * invc);
    }
    *(bf16x8*)&dr[((size_t)kb * PIX + gpix) * 8] = pr;
    *(bf16x8*)&di[((size_t)kb * PIX + gpix) * 8] = pi;
}

// ======================= elementwise / BN =======================
// s1 = x + proj (count division already folded before proj)
__global__ __launch_bounds__(256) void combine1_kernel(
    const float* __restrict__ xr, const float* __restrict__ xi,
    const float* __restrict__ pr, const float* __restrict__ pi,
    float* __restrict__ sr, float* __restrict__ si)
{
    int e = blockIdx.x * 256 + threadIdx.x;
    if (e >= 96 * PIX) return;
    sr[e] = xr[e] + pr[e];
    si[e] = xi[e] + pi[e];
}

__global__ __launch_bounds__(256) void bn_stats_kernel(
    const float* __restrict__ sr, const float* __restrict__ si,
    float* __restrict__ stats)
{
    int cc = blockIdx.x;
    const float* base = (cc < 96) ? (sr + (size_t)cc * PIX) : (si + (size_t)(cc - 96) * PIX);
    float s = 0.f, s2 = 0.f;
    for (int i = threadIdx.x; i < PIX; i += 256) {
        float v = base[i];
        s += v; s2 += v * v;
    }
    __shared__ float red[256], red2[256];
    red[threadIdx.x] = s; red2[threadIdx.x] = s2;
    __syncthreads();
    for (int off = 128; off > 0; off >>= 1) {
        if (threadIdx.x < off) {
            red[threadIdx.x]  += red[threadIdx.x + off];
            red2[threadIdx.x] += red2[threadIdx.x + off];
        }
        __syncthreads();
    }
    if (threadIdx.x == 0) {
        float mean = red[0] / (float)PIX;
        float var  = red2[0] / (float)PIX - mean * mean;
        stats[cc * 2]     = mean;
        stats[cc * 2 + 1] = rsqrtf(var + 1e-5f);
    }
}

__global__ __launch_bounds__(256) void bn_apply_kernel(
    const float* __restrict__ sr, const float* __restrict__ si,
    const float* __restrict__ gr, const float* __restrict__ br,
    const float* __restrict__ gi, const float* __restrict__ bi,
    const float* __restrict__ stats,
    float* __restrict__ outr, float* __restrict__ outi)
{
    int e = blockIdx.x * 256 + threadIdx.x;
    if (e >= 96 * PIX) return;
    int ch = e / PIX;
    float mr = stats[ch * 2],        isr = stats[ch * 2 + 1];
    float mi = stats[(96 + ch) * 2], isi = stats[(96 + ch) * 2 + 1];
    outr[e] = gr[ch] * (sr[e] - mr) * isr + br[ch];
    outi[e] = gi[ch] * (si[e] - mi) * isi + bi[ch];
}

// m += bn1(s1)  (residual add with BN1 recomputed from stats; avoids x1 fp32 buffer)
__global__ __launch_bounds__(256) void add_bn_kernel(
    const float* __restrict__ sr, const float* __restrict__ si,
    const float* __restrict__ gr, const float* __restrict__ br,
    const float* __restrict__ gi, const float* __restrict__ bi,
    const float* __restrict__ stats,
    float* __restrict__ mr_, float* __restrict__ mi_)
{
    int e = blockIdx.x * 256 + threadIdx.x;
    if (e >= 96 * PIX) return;
    int ch = e / PIX;
    float mr = stats[ch * 2],        isr = stats[ch * 2 + 1];
    float mi = stats[(96 + ch) * 2], isi = stats[(96 + ch) * 2 + 1];
    mr_[e] += gr[ch] * (sr[e] - mr) * isr + br[ch];
    mi_[e] += gi[ch] * (si[e] - mi) * isi + bi[ch];
}

// cgelu on the bf16 k8-packed mlp hidden buffer, in place
__global__ __launch_bounds__(256) void cgelu_pack_kernel(
    unsigned short* __restrict__ hr, unsigned short* __restrict__ hi)
{
    size_t e = ((size_t)blockIdx.x * 256 + threadIdx.x) * 8;
    bf16x8 vr = *(bf16x8*)&hr[e];
    bf16x8 vi = *(bf16x8*)&hi[e];
#pragma unroll
    for (int j = 0; j < 8; ++j) {
        float a = bf2f(((unsigned short*)&vr)[j]);
        float b = bf2f(((unsigned short*)&vi)[j]);
        float mag = sqrtf(a * a + b * b);
        float ge = mag * 0.5f * (1.0f + erff(mag * 0.70710678118654752f));
        float f = ge / (mag + 1e-8f);
        ((unsigned short*)&vr)[j] = f2bf(a * f);
        ((unsigned short*)&vi)[j] = f2bf(b * f);
    }
    *(bf16x8*)&hr[e] = vr;
    *(bf16x8*)&hi[e] = vi;
}

// ======================= launch =======================
extern "C" void kernel_launch(void* const* d_in, const int* in_sizes, int n_in,
                              void* d_out, int out_size, void* d_ws, size_t ws_size,
                              hipStream_t stream)
{
    const float* x_r     = (const float*)d_in[0];
    const float* x_i     = (const float*)d_in[1];
    const float* qkv_wr  = (const float*)d_in[2];
    const float* qkv_wi  = (const float*)d_in[3];
    const float* proj_wr = (const float*)d_in[4];
    const float* proj_wi = (const float*)d_in[5];
    const float* rel     = (const float*)d_in[6];
    const float* mlp1_wr = (const float*)d_in[7];
    const float* mlp1_wi = (const float*)d_in[8];
    const float* mlp2_wr = (const float*)d_in[9];
    const float* mlp2_wi = (const float*)d_in[10];
    const float* n1_gr   = (const float*)d_in[11];
    const float* n1_br   = (const float*)d_in[12];
    const float* n1_gi   = (const float*)d_in[13];
    const float* n1_bi   = (const float*)d_in[14];
    const float* n2_gr   = (const float*)d_in[15];
    const float* n2_br   = (const float*)d_in[16];
    const float* n2_gi   = (const float*)d_in[17];
    const float* n2_bi   = (const float*)d_in[18];

    const size_t P = PIX;
    char* base = (char*)d_ws;

    // layout (all 16B-aligned):
    unsigned short* Dr = (unsigned short*)base;           // 96*P packed operand
    unsigned short* Di = Dr + 96 * P;
    float* B_r = (float*)(Di + 96 * P);                   // s1 fp32 planar
    float* B_i = B_r + 96 * P;
    char*  R   = (char*)(B_i + 96 * P);                   // 97.3 MB overlay region
    unsigned short* qkvb = (unsigned short*)R;            // 576*P ushorts
    unsigned short* wout = qkvb + 576 * P;                // NWIN*32*96*2 ushorts
    float* A_r = (float*)R;                               // proj out / mlp2 out (m/s2)
    float* A_i = A_r + 96 * P;
    unsigned short* hid_r = (unsigned short*)(A_i + 96 * P);   // 384*P packed hidden
    unsigned short* hid_i = hid_r + 384 * P;
    unsigned short* Wb = wout + (size_t)NWIN * 32 * 96 * 2;    // weights bf16
    float* stats1 = (float*)(Wb + 331776);
    float* stats2 = stats1 + 384;

    unsigned short* wq_r  = Wb;            unsigned short* wq_i  = Wb + 27648;  unsigned short* wq_ni = Wb + 55296;
    unsigned short* wp_r  = Wb + 82944;    unsigned short* wp_i  = Wb + 92160;  unsigned short* wp_ni = Wb + 101376;
    unsigned short* w1_r  = Wb + 110592;   unsigned short* w1_i  = Wb + 147456; unsigned short* w1_ni = Wb + 184320;
    unsigned short* w2_r  = Wb + 221184;   unsigned short* w2_i  = Wb + 258048; unsigned short* w2_ni = Wb + 294912;

    float* out_r = (float*)d_out;
    float* out_i = out_r + 96 * P;

    dim3 blk(256);

    // 0. weights -> bf16 (+ negated imag)
    wconv_kernel<<<dim3(108), blk, 0, stream>>>(qkv_wr, qkv_wi, wq_r, wq_i, wq_ni, 27648);
    wconv_kernel<<<dim3(36),  blk, 0, stream>>>(proj_wr, proj_wi, wp_r, wp_i, wp_ni, 9216);
    wconv_kernel<<<dim3(144), blk, 0, stream>>>(mlp1_wr, mlp1_wi, w1_r, w1_i, w1_ni, 36864);
    wconv_kernel<<<dim3(144), blk, 0, stream>>>(mlp2_wr, mlp2_wi, w2_r, w2_i, w2_ni, 36864);

    // 1. pack x
    pack_kernel<<<dim3(144, 12), blk, 0, stream>>>(x_r, x_i, Dr, Di, PIX);
    // 2. QKV gemm -> pixel-major interleaved bf16 qkvb
    cgemm_mfma_kernel<96, 2><<<dim3(9, 144), blk, 0, stream>>>(
        wq_r, wq_i, wq_ni, Dr, Di, nullptr, nullptr, qkvb, nullptr, PIX);
    // 3. attention -> per-window bf16 outputs (no atomics)
    attn_kernel<<<dim3(NWIN * 6), blk, 0, stream>>>(qkvb, rel, wout);
    // 4. fold + /counts + pack for proj
    fold_pack_kernel<<<dim3(1728), blk, 0, stream>>>(wout, Dr, Di);
    // 5. proj gemm -> fp32 planar A
    cgemm_mfma_kernel<96, 0><<<dim3(3, 144), blk, 0, stream>>>(
        wp_r, wp_i, wp_ni, Dr, Di, A_r, A_i, nullptr, nullptr, PIX);
    // 6. s1 = x + proj -> B
    combine1_kernel<<<dim3(13824), blk, 0, stream>>>(x_r, x_i, A_r, A_i, B_r, B_i);
    // 7. BN1 stats
    bn_stats_kernel<<<dim3(192), blk, 0, stream>>>(B_r, B_i, stats1);
    // 8. pack + BN1 apply -> packed x1
    pack_bn_kernel<<<dim3(144, 12), blk, 0, stream>>>(B_r, B_i, stats1,
        n1_gr, n1_br, n1_gi, n1_bi, Dr, Di, PIX);
    // 9. mlp1 gemm -> packed bf16 hidden
    cgemm_mfma_kernel<96, 1><<<dim3(12, 144), blk, 0, stream>>>(
        w1_r, w1_i, w1_ni, Dr, Di, nullptr, nullptr, hid_r, hid_i, PIX);
    // 10. cgelu in place
    cgelu_pack_kernel<<<dim3(6912), blk, 0, stream>>>(hid_r, hid_i);
    // 11. mlp2 gemm -> m (A region; hidden lives above it, no overlap)
    cgemm_mfma_kernel<384, 0><<<dim3(3, 144), blk, 0, stream>>>(
        w2_r, w2_i, w2_ni, hid_r, hid_i, A_r, A_i, nullptr, nullptr, PIX);
    // 12. s2 = m + bn1(s1)  (in place on A)
    add_bn_kernel<<<dim3(13824), blk, 0, stream>>>(B_r, B_i,
        n1_gr, n1_br, n1_gi, n1_bi, stats1, A_r, A_i);
    // 13. BN2 -> out
    bn_stats_kernel<<<dim3(192), blk, 0, stream>>>(A_r, A_i, stats2);
    bn_apply_kernel<<<dim3(13824), blk, 0, stream>>>(A_r, A_i,
        n2_gr, n2_br, n2_gi, n2_bi, stats2, out_r, out_i);
}

// Round 4
// 442.758 us; speedup vs baseline: 4.0024x; 1.4899x over previous
//
#include <hip/hip_runtime.h>
#include <math.h>

#define PIX 36864          // 192*192
#define IMW 192
#define NWIN 4465          // 47*95
#define NWIN_W 95
#define NTASK (NWIN * 6)

typedef short bf16x8 __attribute__((ext_vector_type(8)));
typedef short bf16x4 __attribute__((ext_vector_type(4)));
typedef float floatx4 __attribute__((ext_vector_type(4)));

__device__ __forceinline__ unsigned short f2bf(float f) {
    union { float f; unsigned u; } v; v.f = f;
    unsigned r = v.u + 0x7fff + ((v.u >> 16) & 1);   // RNE
    return (unsigned short)(r >> 16);
}
__device__ __forceinline__ float bf2f(unsigned short b) {
    union { unsigned u; float f; } v; v.u = ((unsigned)b) << 16;
    return v.f;
}

// ======================= weight convert: fp32 -> bf16 (+negated imag) =======================
__global__ __launch_bounds__(256) void wconv_kernel(
    const float* __restrict__ wr, const float* __restrict__ wi,
    unsigned short* __restrict__ outr, unsigned short* __restrict__ outi,
    unsigned short* __restrict__ outni, int n)
{
    int e = blockIdx.x * 256 + threadIdx.x;
    if (e >= n) return;
    outr[e] = f2bf(wr[e]);
    unsigned short b = f2bf(wi[e]);
    outi[e]  = b;
    outni[e] = b ^ 0x8000;
}

// ======================= pack: fp32 planar [k][n] -> bf16 k8-packed =======================
__global__ __launch_bounds__(256) void pack_kernel(
    const float* __restrict__ sr, const float* __restrict__ si,
    unsigned short* __restrict__ dr, unsigned short* __restrict__ di, int N)
{
    int n  = blockIdx.x * 256 + threadIdx.x;
    int kb = blockIdx.y;
    bf16x8 vr, vi;
#pragma unroll
    for (int j = 0; j < 8; ++j) {
        ((unsigned short*)&vr)[j] = f2bf(sr[(size_t)(kb * 8 + j) * N + n]);
        ((unsigned short*)&vi)[j] = f2bf(si[(size_t)(kb * 8 + j) * N + n]);
    }
    *(bf16x8*)&dr[((size_t)kb * N + n) * 8] = vr;
    *(bf16x8*)&di[((size_t)kb * N + n) * 8] = vi;
}

// pack + BN1 apply fused
__global__ __launch_bounds__(256) void pack_bn_kernel(
    const float* __restrict__ sr, const float* __restrict__ si,
    const float* __restrict__ stats,
    const float* __restrict__ gr, const float* __restrict__ br,
    const float* __restrict__ gi, const float* __restrict__ bi,
    unsigned short* __restrict__ dr, unsigned short* __restrict__ di, int N)
{
    int n  = blockIdx.x * 256 + threadIdx.x;
    int kb = blockIdx.y;
    bf16x8 vr, vi;
#pragma unroll
    for (int j = 0; j < 8; ++j) {
        int ch = kb * 8 + j;
        float mr = stats[ch * 2],        isr = stats[ch * 2 + 1];
        float mi = stats[(96 + ch) * 2], isi = stats[(96 + ch) * 2 + 1];
        ((unsigned short*)&vr)[j] = f2bf(gr[ch] * (sr[(size_t)ch * N + n] - mr) * isr + br[ch]);
        ((unsigned short*)&vi)[j] = f2bf(gi[ch] * (si[(size_t)ch * N + n] - mi) * isi + bi[ch]);
    }
    *(bf16x8*)&dr[((size_t)kb * N + n) * 8] = vr;
    *(bf16x8*)&di[((size_t)kb * N + n) * 8] = vi;
}

// ======================= complex GEMM via MFMA =======================
// STORE: 0 = fp32 planar, 1 = k8-packed bf16,
//        2 = pixel-major qkvb slot [re d0..15][im d0..15] per (pix,which,head)
template<int K, int STORE>
__global__ __launch_bounds__(256, 2) void cgemm_mfma_kernel(
    const unsigned short* __restrict__ Wr, const unsigned short* __restrict__ Wi,
    const unsigned short* __restrict__ Wni,
    const unsigned short* __restrict__ Xr, const unsigned short* __restrict__ Xi,
    float* __restrict__ Yr, float* __restrict__ Yi,
    unsigned short* __restrict__ Pr, unsigned short* __restrict__ Pi,
    int N)
{
    const int lane = threadIdx.x & 63;
    const int wave = threadIdx.x >> 6;
    const int g = lane >> 4;
    const int r = lane & 15;
    const int m0 = blockIdx.x * 32;
    const int n0 = blockIdx.y * 256 + wave * 64;

    floatx4 accR[2][4], accI[2][4];
#pragma unroll
    for (int t = 0; t < 2; ++t)
#pragma unroll
        for (int j = 0; j < 4; ++j) {
            accR[t][j] = (floatx4){0.f, 0.f, 0.f, 0.f};
            accI[t][j] = (floatx4){0.f, 0.f, 0.f, 0.f};
        }

    for (int kc = 0; kc < K; kc += 32) {
        bf16x8 awr[2], awi[2], awni[2];
#pragma unroll
        for (int t = 0; t < 2; ++t) {
            size_t wb = (size_t)(m0 + t * 16 + r) * K + kc + g * 8;
            awr[t]  = *(const bf16x8*)&Wr[wb];
            awi[t]  = *(const bf16x8*)&Wi[wb];
            awni[t] = *(const bf16x8*)&Wni[wb];
        }
        bf16x8 bxr[4], bxi[4];
        const size_t krow = (size_t)((kc >> 3) + g);
#pragma unroll
        for (int j = 0; j < 4; ++j) {
            size_t off = (krow * N + n0 + j * 16 + r) * 8;
            bxr[j] = *(const bf16x8*)&Xr[off];
            bxi[j] = *(const bf16x8*)&Xi[off];
        }
#pragma unroll
        for (int t = 0; t < 2; ++t)
#pragma unroll
            for (int j = 0; j < 4; ++j) {
                accR[t][j] = __builtin_amdgcn_mfma_f32_16x16x32_bf16(awr[t],  bxr[j], accR[t][j], 0, 0, 0);
                accR[t][j] = __builtin_amdgcn_mfma_f32_16x16x32_bf16(awni[t], bxi[j], accR[t][j], 0, 0, 0);
                accI[t][j] = __builtin_amdgcn_mfma_f32_16x16x32_bf16(awr[t],  bxi[j], accI[t][j], 0, 0, 0);
                accI[t][j] = __builtin_amdgcn_mfma_f32_16x16x32_bf16(awi[t],  bxr[j], accI[t][j], 0, 0, 0);
            }
    }

    if (STORE == 0) {
#pragma unroll
        for (int t = 0; t < 2; ++t)
#pragma unroll
            for (int j = 0; j < 4; ++j) {
                int col = n0 + j * 16 + r;
#pragma unroll
                for (int reg = 0; reg < 4; ++reg) {
                    int row = m0 + t * 16 + g * 4 + reg;
                    Yr[(size_t)row * N + col] = accR[t][j][reg];
                    Yi[(size_t)row * N + col] = accI[t][j][reg];
                }
            }
    } else if (STORE == 1) {
#pragma unroll
        for (int t = 0; t < 2; ++t)
#pragma unroll
            for (int j = 0; j < 4; ++j) {
                int col = n0 + j * 16 + r;
                size_t rowblk = (size_t)((m0 + t * 16 + g * 4) >> 3);
                int sub = (g & 1) * 4;
                bf16x4 pr, pi;
#pragma unroll
                for (int reg = 0; reg < 4; ++reg) {
                    ((unsigned short*)&pr)[reg] = f2bf(accR[t][j][reg]);
                    ((unsigned short*)&pi)[reg] = f2bf(accI[t][j][reg]);
                }
                *(bf16x4*)&Pr[(rowblk * N + col) * 8 + sub] = pr;
                *(bf16x4*)&Pi[(rowblk * N + col) * 8 + sub] = pi;
            }
    } else {
        // comp-planar slot: base + d for re, base + 16 + d for im; d = g*4+reg
#pragma unroll
        for (int t = 0; t < 2; ++t) {
            int ch0 = m0 + t * 16;
            int which = ch0 / 96;
            int hh = (ch0 % 96) / 16;
#pragma unroll
            for (int j = 0; j < 4; ++j) {
                int col = n0 + j * 16 + r;
                bf16x4 pr, pi;
#pragma unroll
                for (int reg = 0; reg < 4; ++reg) {
                    ((unsigned short*)&pr)[reg] = f2bf(accR[t][j][reg]);
                    ((unsigned short*)&pi)[reg] = f2bf(accI[t][j][reg]);
                }
                size_t sb = (((size_t)col * 3 + which) * 6 + hh) * 32;
                *(bf16x4*)&Pr[sb + g * 4]      = pr;
                *(bf16x4*)&Pr[sb + 16 + g * 4] = pi;
            }
        }
    }
}

// ======================= MFMA attention: one wave per (window, head) =======================
// S = scale*Q·conj(K)^T + bias via 16x16x32 bf16 MFMA (K-dim = [re|im] concat),
// magnitude-softmax in registers (C-layout), transpose through padded LDS,
// P = attn·V via k=2m+comp interleave. Writes wout[win][pix][ch][re,im] bf16.
__global__ __launch_bounds__(256) void attn_mfma_kernel(
    const unsigned short* __restrict__ qkvb,
    const float* __restrict__ rel,
    unsigned short* __restrict__ wout)
{
    __shared__ unsigned aLDS[4][32 * 36];   // attn weights, stride 36 dwords (2-way-only conflicts)
    __shared__ unsigned vLDS[4][32 * 17];   // V pairs [m][d], stride 17

    const int wv   = threadIdx.x >> 6;
    const int lane = threadIdx.x & 63;
    const int lr   = lane & 15;
    const int g    = lane >> 4;

    int t = blockIdx.x * 4 + wv;
    if (t >= NTASK) t = NTASK - 1;          // duplicate last task; identical writes are benign
    const int w = t / 6, h = t % 6;
    const int nh = w / NWIN_W, nw = w % NWIN_W;
    const int r0 = nh * 4, c0 = nw * 2;

    unsigned* AL = aLDS[wv];
    unsigned* VL = vLDS[wv];

    auto slot = [&](int p, int which) -> size_t {
        int gpix = (r0 + (p >> 2)) * IMW + c0 + (p & 3);
        return (((size_t)gpix * 3 + which) * 6 + h) * 32;
    };

    // ---- stage V into LDS as (vr,vi) dword pairs [m][d] ----
    {
        int m = lane & 31;
        int half = lane >> 5;
        size_t sv = slot(m, 2);
        const bf16x8 vr = *(const bf16x8*)&qkvb[sv + half * 8];
        const bf16x8 vi = *(const bf16x8*)&qkvb[sv + 16 + half * 8];
#pragma unroll
        for (int j = 0; j < 8; ++j) {
            unsigned pk = (unsigned)(unsigned short)vr[j] |
                          ((unsigned)(unsigned short)vi[j] << 16);
            VL[m * 17 + half * 8 + j] = pk;
        }
    }

    // ---- Q/K fragments from global (16B loads) ----
    bf16x8 Are[2], Aim[2], Bre[2], Bim[2];
    const bool hi = g >= 2;
#pragma unroll
    for (int tt = 0; tt < 2; ++tt) {
        size_t sq = slot(tt * 16 + lr, 0);
        bf16x8 qa = *(const bf16x8*)&qkvb[sq + (g & 1) * 8];        // qr half
        bf16x8 qb = *(const bf16x8*)&qkvb[sq + 16 + (g & 1) * 8];   // qi half
        size_t sk = slot(tt * 16 + lr, 1);
        bf16x8 ka = *(const bf16x8*)&qkvb[sk + (g & 1) * 8];        // kr half
        bf16x8 kb = *(const bf16x8*)&qkvb[sk + 16 + (g & 1) * 8];   // ki half
        Are[tt] = hi ? qb : qa;        // [qr | qi]
        Aim[tt] = hi ? qa : qb;        // [qi | qr]
        Bre[tt] = hi ? kb : ka;        // [kr | ki]
        bf16x8 nkb = kb;
        unsigned* u = (unsigned*)&nkb;
        u[0] ^= 0x80008000u; u[1] ^= 0x80008000u; u[2] ^= 0x80008000u; u[3] ^= 0x80008000u;
        Bim[tt] = hi ? nkb : ka;       // [kr | -ki]
    }

    // ---- S = Q·conj(K)^T : 8 MFMAs ----
    const floatx4 z4 = (floatx4){0.f, 0.f, 0.f, 0.f};
    floatx4 Sre[2][2], Sim[2][2];
#pragma unroll
    for (int tn = 0; tn < 2; ++tn)
#pragma unroll
        for (int tm = 0; tm < 2; ++tm) {
            Sre[tn][tm] = __builtin_amdgcn_mfma_f32_16x16x32_bf16(Are[tn], Bre[tm], z4, 0, 0, 0);
            Sim[tn][tm] = __builtin_amdgcn_mfma_f32_16x16x32_bf16(Aim[tn], Bim[tm], z4, 0, 0, 0);
        }

    // ---- scale + bias + magnitude ----
    const float* relh = rel + h * 105;
    float re_[2][2][4], im_[2][2][4], mag[2][2][4];
#pragma unroll
    for (int tn = 0; tn < 2; ++tn)
#pragma unroll
        for (int tm = 0; tm < 2; ++tm) {
            int m = tm * 16 + lr;
            int ym = m >> 2, xm = m & 3;
            int yn = tn * 4 + g;                       // n>>2 ; xn = reg
            int bidx = (yn - ym + 7) * 7 + (3 - xm);   // + reg added below
#pragma unroll
            for (int reg = 0; reg < 4; ++reg) {
                float re = Sre[tn][tm][reg] * 0.25f + relh[bidx + reg];
                float im = Sim[tn][tm][reg] * 0.25f;
                re_[tn][tm][reg] = re;
                im_[tn][tm][reg] = im;
                mag[tn][tm][reg] = sqrtf(re * re + im * im);
            }
        }

    // ---- magnitude softmax per row (reduce across lane&15, both m-tiles local) ----
#pragma unroll
    for (int tn = 0; tn < 2; ++tn)
#pragma unroll
        for (int reg = 0; reg < 4; ++reg) {
            float mx = fmaxf(mag[tn][0][reg], mag[tn][1][reg]);
            mx = fmaxf(mx, __shfl_xor(mx, 1, 64));
            mx = fmaxf(mx, __shfl_xor(mx, 2, 64));
            mx = fmaxf(mx, __shfl_xor(mx, 4, 64));
            mx = fmaxf(mx, __shfl_xor(mx, 8, 64));
            float e0 = expf(mag[tn][0][reg] - mx);
            float e1 = expf(mag[tn][1][reg] - mx);
            float ss = e0 + e1;
            ss += __shfl_xor(ss, 1, 64);
            ss += __shfl_xor(ss, 2, 64);
            ss += __shfl_xor(ss, 4, 64);
            ss += __shfl_xor(ss, 8, 64);
            float inv = 1.0f / ss;
            float f0 = e0 * inv / (mag[tn][0][reg] + 1e-8f);
            float f1 = e1 * inv / (mag[tn][1][reg] + 1e-8f);
            re_[tn][0][reg] *= f0; im_[tn][0][reg] *= f0;
            re_[tn][1][reg] *= f1; im_[tn][1][reg] *= f1;
        }

    // ---- transpose attn weights through LDS into A-fragment layout (k=2m+comp) ----
#pragma unroll
    for (int tn = 0; tn < 2; ++tn)
#pragma unroll
        for (int tm = 0; tm < 2; ++tm)
#pragma unroll
            for (int reg = 0; reg < 4; ++reg) {
                int n = tn * 16 + g * 4 + reg;
                int m = tm * 16 + lr;
                unsigned pk = (unsigned)f2bf(re_[tn][tm][reg]) |
                              ((unsigned)f2bf(im_[tn][tm][reg]) << 16);
                AL[n * 36 + m] = pk;
            }

    __syncthreads();

    // ---- P = attn · V : 8 MFMAs ----
    floatx4 Pre[2] = {z4, z4}, Pim[2] = {z4, z4};
#pragma unroll
    for (int kc = 0; kc < 2; ++kc) {
        bf16x8 Bpr, Bpi;
        unsigned* bpr = (unsigned*)&Bpr;
        unsigned* bpi = (unsigned*)&Bpi;
#pragma unroll
        for (int p = 0; p < 4; ++p) {
            unsigned pv = VL[(kc * 16 + g * 4 + p) * 17 + lr];
            bpr[p] = pv ^ 0x80000000u;            // (vr, -vi)
            bpi[p] = (pv >> 16) | (pv << 16);     // (vi, vr)
        }
#pragma unroll
        for (int tn = 0; tn < 2; ++tn) {
            bf16x8 Af = *(bf16x8*)&AL[(tn * 16 + lr) * 36 + kc * 16 + g * 4];
            Pre[tn] = __builtin_amdgcn_mfma_f32_16x16x32_bf16(Af, Bpr, Pre[tn], 0, 0, 0);
            Pim[tn] = __builtin_amdgcn_mfma_f32_16x16x32_bf16(Af, Bpi, Pim[tn], 0, 0, 0);
        }
    }

    // ---- epilogue: wout[win][pix][ch][re,im] ----
#pragma unroll
    for (int tn = 0; tn < 2; ++tn)
#pragma unroll
        for (int reg = 0; reg < 4; ++reg) {
            int n = tn * 16 + g * 4 + reg;
            int ch = h * 16 + lr;
            unsigned pk = (unsigned)f2bf(Pre[tn][reg]) |
                          ((unsigned)f2bf(Pim[tn][reg]) << 16);
            *(unsigned*)&wout[(((size_t)w * 32 + n) * 96 + ch) * 2] = pk;
        }
}

// ======================= fold + count-div + pack for proj =======================
__global__ __launch_bounds__(256) void fold_pack_kernel(
    const unsigned short* __restrict__ wout,
    unsigned short* __restrict__ dr, unsigned short* __restrict__ di)
{
    int e = blockIdx.x * 256 + threadIdx.x;   // PIX*12
    int gpix = e / 12;
    int kb   = e % 12;
    int r = gpix / IMW, c = gpix % IMW;
    int nh0 = (r >= 7) ? ((r - 4) >> 2) : 0;
    int nh1 = min(46, r >> 2);
    int nw0 = (c >= 3) ? ((c - 2) >> 1) : 0;
    int nw1 = min(94, c >> 1);

    float accr[8] = {0,0,0,0,0,0,0,0}, acci[8] = {0,0,0,0,0,0,0,0};
    int cnt = 0;
    for (int nh = nh0; nh <= nh1; ++nh)
        for (int nw = nw0; nw <= nw1; ++nw) {
            int win = nh * NWIN_W + nw;
            int n = (r - nh * 4) * 4 + (c - nw * 2);
            const unsigned short* src = &wout[(((size_t)win * 32 + n) * 96 + kb * 8) * 2];
            bf16x8 a = *(const bf16x8*)&src[0];
            bf16x8 b = *(const bf16x8*)&src[8];
#pragma unroll
            for (int j = 0; j < 4; ++j) {
                accr[j]     += bf2f((unsigned short)a[j*2]);
                acci[j]     += bf2f((unsigned short)a[j*2+1]);
                accr[4 + j] += bf2f((unsigned short)b[j*2]);
                acci[4 + j] += bf2f((unsigned short)b[j*2+1]);
            }
            ++cnt;
        }
    float invc = 1.0f / ((float)cnt + 1e-8f);
    bf16x8 pr, pi;
#pragma unroll
    for (int j = 0; j < 8; ++j) {
        ((unsigned short*)&pr)[j] = f2bf(accr[j] * invc);
        ((unsigned short*)&pi)[j] = f2bf(acci[j] * invc);
    }
    *(bf16x8*)&dr[((size_t)kb * PIX + gpix) * 8] = pr;
    *(bf16x8*)&di[((size_t)kb * PIX + gpix) * 8] = pi;
}

// ======================= elementwise / BN =======================
__global__ __launch_bounds__(256) void combine1_kernel(
    const float* __restrict__ xr, const float* __restrict__ xi,
    const float* __restrict__ pr, const float* __restrict__ pi,
    float* __restrict__ sr, float* __restrict__ si)
{
    int e = blockIdx.x * 256 + threadIdx.x;
    if (e >= 96 * PIX) return;
    sr[e] = xr[e] + pr[e];
    si[e] = xi[e] + pi[e];
}

__global__ __launch_bounds__(256) void bn_stats_kernel(
    const float* __restrict__ sr, const float* __restrict__ si,
    float* __restrict__ stats)
{
    int cc = blockIdx.x;
    const float* base = (cc < 96) ? (sr + (size_t)cc * PIX) : (si + (size_t)(cc - 96) * PIX);
    float s = 0.f, s2 = 0.f;
    for (int i = threadIdx.x; i < PIX; i += 256) {
        float v = base[i];
        s += v; s2 += v * v;
    }
    __shared__ float red[256], red2[256];
    red[threadIdx.x] = s; red2[threadIdx.x] = s2;
    __syncthreads();
    for (int off = 128; off > 0; off >>= 1) {
        if (threadIdx.x < off) {
            red[threadIdx.x]  += red[threadIdx.x + off];
            red2[threadIdx.x] += red2[threadIdx.x + off];
        }
        __syncthreads();
    }
    if (threadIdx.x == 0) {
        float mean = red[0] / (float)PIX;
        float var  = red2[0] / (float)PIX - mean * mean;
        stats[cc * 2]     = mean;
        stats[cc * 2 + 1] = rsqrtf(var + 1e-5f);
    }
}

__global__ __launch_bounds__(256) void bn_apply_kernel(
    const float* __restrict__ sr, const float* __restrict__ si,
    const float* __restrict__ gr, const float* __restrict__ br,
    const float* __restrict__ gi, const float* __restrict__ bi,
    const float* __restrict__ stats,
    float* __restrict__ outr, float* __restrict__ outi)
{
    int e = blockIdx.x * 256 + threadIdx.x;
    if (e >= 96 * PIX) return;
    int ch = e / PIX;
    float mr = stats[ch * 2],        isr = stats[ch * 2 + 1];
    float mi = stats[(96 + ch) * 2], isi = stats[(96 + ch) * 2 + 1];
    outr[e] = gr[ch] * (sr[e] - mr) * isr + br[ch];
    outi[e] = gi[ch] * (si[e] - mi) * isi + bi[ch];
}

__global__ __launch_bounds__(256) void add_bn_kernel(
    const float* __restrict__ sr, const float* __restrict__ si,
    const float* __restrict__ gr, const float* __restrict__ br,
    const float* __restrict__ gi, const float* __restrict__ bi,
    const float* __restrict__ stats,
    float* __restrict__ mr_, float* __restrict__ mi_)
{
    int e = blockIdx.x * 256 + threadIdx.x;
    if (e >= 96 * PIX) return;
    int ch = e / PIX;
    float mr = stats[ch * 2],        isr = stats[ch * 2 + 1];
    float mi = stats[(96 + ch) * 2], isi = stats[(96 + ch) * 2 + 1];
    mr_[e] += gr[ch] * (sr[e] - mr) * isr + br[ch];
    mi_[e] += gi[ch] * (si[e] - mi) * isi + bi[ch];
}

__global__ __launch_bounds__(256) void cgelu_pack_kernel(
    unsigned short* __restrict__ hr, unsigned short* __restrict__ hi)
{
    size_t e = ((size_t)blockIdx.x * 256 + threadIdx.x) * 8;
    bf16x8 vr = *(bf16x8*)&hr[e];
    bf16x8 vi = *(bf16x8*)&hi[e];
#pragma unroll
    for (int j = 0; j < 8; ++j) {
        float a = bf2f(((unsigned short*)&vr)[j]);
        float b = bf2f(((unsigned short*)&vi)[j]);
        float mag = sqrtf(a * a + b * b);
        float ge = mag * 0.5f * (1.0f + erff(mag * 0.70710678118654752f));
        float f = ge / (mag + 1e-8f);
        ((unsigned short*)&vr)[j] = f2bf(a * f);
        ((unsigned short*)&vi)[j] = f2bf(b * f);
    }
    *(bf16x8*)&hr[e] = vr;
    *(bf16x8*)&hi[e] = vi;
}

// ======================= launch =======================
extern "C" void kernel_launch(void* const* d_in, const int* in_sizes, int n_in,
                              void* d_out, int out_size, void* d_ws, size_t ws_size,
                              hipStream_t stream)
{
    const float* x_r     = (const float*)d_in[0];
    const float* x_i     = (const float*)d_in[1];
    const float* qkv_wr  = (const float*)d_in[2];
    const float* qkv_wi  = (const float*)d_in[3];
    const float* proj_wr = (const float*)d_in[4];
    const float* proj_wi = (const float*)d_in[5];
    const float* rel     = (const float*)d_in[6];
    const float* mlp1_wr = (const float*)d_in[7];
    const float* mlp1_wi = (const float*)d_in[8];
    const float* mlp2_wr = (const float*)d_in[9];
    const float* mlp2_wi = (const float*)d_in[10];
    const float* n1_gr   = (const float*)d_in[11];
    const float* n1_br   = (const float*)d_in[12];
    const float* n1_gi   = (const float*)d_in[13];
    const float* n1_bi   = (const float*)d_in[14];
    const float* n2_gr   = (const float*)d_in[15];
    const float* n2_br   = (const float*)d_in[16];
    const float* n2_gi   = (const float*)d_in[17];
    const float* n2_bi   = (const float*)d_in[18];

    const size_t P = PIX;
    char* base = (char*)d_ws;

    unsigned short* Dr = (unsigned short*)base;           // 96*P packed operand
    unsigned short* Di = Dr + 96 * P;
    float* B_r = (float*)(Di + 96 * P);                   // s1 fp32 planar
    float* B_i = B_r + 96 * P;
    char*  R   = (char*)(B_i + 96 * P);                   // overlay region
    unsigned short* qkvb = (unsigned short*)R;            // 576*P ushorts
    unsigned short* wout = qkvb + 576 * P;                // NWIN*32*96*2 ushorts
    float* A_r = (float*)R;                               // proj out / mlp2 out
    float* A_i = A_r + 96 * P;
    unsigned short* hid_r = (unsigned short*)(A_i + 96 * P);   // 384*P packed hidden
    unsigned short* hid_i = hid_r + 384 * P;
    unsigned short* Wb = wout + (size_t)NWIN * 32 * 96 * 2;    // weights bf16
    float* stats1 = (float*)(Wb + 331776);
    float* stats2 = stats1 + 384;

    unsigned short* wq_r  = Wb;            unsigned short* wq_i  = Wb + 27648;  unsigned short* wq_ni = Wb + 55296;
    unsigned short* wp_r  = Wb + 82944;    unsigned short* wp_i  = Wb + 92160;  unsigned short* wp_ni = Wb + 101376;
    unsigned short* w1_r  = Wb + 110592;   unsigned short* w1_i  = Wb + 147456; unsigned short* w1_ni = Wb + 184320;
    unsigned short* w2_r  = Wb + 221184;   unsigned short* w2_i  = Wb + 258048; unsigned short* w2_ni = Wb + 294912;

    float* out_r = (float*)d_out;
    float* out_i = out_r + 96 * P;

    dim3 blk(256);

    wconv_kernel<<<dim3(108), blk, 0, stream>>>(qkv_wr, qkv_wi, wq_r, wq_i, wq_ni, 27648);
    wconv_kernel<<<dim3(36),  blk, 0, stream>>>(proj_wr, proj_wi, wp_r, wp_i, wp_ni, 9216);
    wconv_kernel<<<dim3(144), blk, 0, stream>>>(mlp1_wr, mlp1_wi, w1_r, w1_i, w1_ni, 36864);
    wconv_kernel<<<dim3(144), blk, 0, stream>>>(mlp2_wr, mlp2_wi, w2_r, w2_i, w2_ni, 36864);

    // 1. pack x
    pack_kernel<<<dim3(144, 12), blk, 0, stream>>>(x_r, x_i, Dr, Di, PIX);
    // 2. QKV gemm -> comp-planar pixel-major qkvb
    cgemm_mfma_kernel<96, 2><<<dim3(9, 144), blk, 0, stream>>>(
        wq_r, wq_i, wq_ni, Dr, Di, nullptr, nullptr, qkvb, nullptr, PIX);
    // 3. MFMA attention -> per-window bf16 outputs
    attn_mfma_kernel<<<dim3((NTASK + 3) / 4), blk, 0, stream>>>(qkvb, rel, wout);
    // 4. fold + /counts + pack for proj
    fold_pack_kernel<<<dim3(1728), blk, 0, stream>>>(wout, Dr, Di);
    // 5. proj gemm -> fp32 planar A
    cgemm_mfma_kernel<96, 0><<<dim3(3, 144), blk, 0, stream>>>(
        wp_r, wp_i, wp_ni, Dr, Di, A_r, A_i, nullptr, nullptr, PIX);
    // 6. s1 = x + proj -> B
    combine1_kernel<<<dim3(13824), blk, 0, stream>>>(x_r, x_i, A_r, A_i, B_r, B_i);
    // 7. BN1 stats
    bn_stats_kernel<<<dim3(192), blk, 0, stream>>>(B_r, B_i, stats1);
    // 8. pack + BN1 apply -> packed x1
    pack_bn_kernel<<<dim3(144, 12), blk, 0, stream>>>(B_r, B_i, stats1,
        n1_gr, n1_br, n1_gi, n1_bi, Dr, Di, PIX);
    // 9. mlp1 gemm -> packed bf16 hidden
    cgemm_mfma_kernel<96, 1><<<dim3(12, 144), blk, 0, stream>>>(
        w1_r, w1_i, w1_ni, Dr, Di, nullptr, nullptr, hid_r, hid_i, PIX);
    // 10. cgelu in place
    cgelu_pack_kernel<<<dim3(6912), blk, 0, stream>>>(hid_r, hid_i);
    // 11. mlp2 gemm -> m (A region)
    cgemm_mfma_kernel<384, 0><<<dim3(3, 144), blk, 0, stream>>>(
        w2_r, w2_i, w2_ni, hid_r, hid_i, A_r, A_i, nullptr, nullptr, PIX);
    // 12. s2 = m + bn1(s1)
    add_bn_kernel<<<dim3(13824), blk, 0, stream>>>(B_r, B_i,
        n1_gr, n1_br, n1_gi, n1_bi, stats1, A_r, A_i);
    // 13. BN2 -> out
    bn_stats_kernel<<<dim3(192), blk, 0, stream>>>(A_r, A_i, stats2);
    bn_apply_kernel<<<dim3(13824), blk, 0, stream>>>(A_r, A_i,
        n2_gr, n2_br, n2_gi, n2_bi, stats2, out_r, out_i);
}